// Round 1
// baseline (2081.472 us; speedup 1.0000x reference)
//
#include <hip/hip_runtime.h>
#include <hip/hip_bf16.h>
#include <cstdint>

#define B_ 8
#define S_ 4096
#define DM 1024
#define H_ 16
#define DN 64      // head dim
#define CH 64      // chunk length
#define NC 64      // chunks per sequence
#define E_ 1040    // in_proj output dim (1024 + 16)

// ===================== fp32 GEMM: C[m][n] = sum_k A[m][k]*B[n][k] =====================
#define BM 128
#define BN 128
#define BK 16

__global__ __launch_bounds__(256) void sgemm_abt(
    const float* __restrict__ A, int lda,
    const float* __restrict__ Bm, int ldb,
    float* __restrict__ C, int ldc,
    int M, int N, int K)
{
  __shared__ float As[BK][BM + 4];
  __shared__ float Bs[BK][BN + 4];
  const int m0 = blockIdx.y * BM;
  const int n0 = blockIdx.x * BN;
  const int t  = threadIdx.x;
  const int tm = (t >> 4) * 8;
  const int tn = (t & 15) * 8;
  float acc[8][8];
#pragma unroll
  for (int i = 0; i < 8; ++i)
#pragma unroll
    for (int j = 0; j < 8; ++j) acc[i][j] = 0.f;

  for (int k0 = 0; k0 < K; k0 += BK) {
#pragma unroll
    for (int i = 0; i < 2; ++i) {
      int f  = t + i * 256;          // 0..511
      int m  = f >> 2;               // 0..127
      int kq = (f & 3) << 2;         // 0,4,8,12
      float4 v = *reinterpret_cast<const float4*>(&A[(size_t)(m0 + m) * lda + k0 + kq]);
      As[kq + 0][m] = v.x; As[kq + 1][m] = v.y; As[kq + 2][m] = v.z; As[kq + 3][m] = v.w;
      float4 w = make_float4(0.f, 0.f, 0.f, 0.f);
      if (n0 + m < N)
        w = *reinterpret_cast<const float4*>(&Bm[(size_t)(n0 + m) * ldb + k0 + kq]);
      Bs[kq + 0][m] = w.x; Bs[kq + 1][m] = w.y; Bs[kq + 2][m] = w.z; Bs[kq + 3][m] = w.w;
    }
    __syncthreads();
#pragma unroll
    for (int kk = 0; kk < BK; ++kk) {
      float a[8], bb[8];
#pragma unroll
      for (int i = 0; i < 8; ++i) a[i] = As[kk][tm + i];
#pragma unroll
      for (int j = 0; j < 8; ++j) bb[j] = Bs[kk][tn + j];
#pragma unroll
      for (int i = 0; i < 8; ++i)
#pragma unroll
        for (int j = 0; j < 8; ++j)
          acc[i][j] = fmaf(a[i], bb[j], acc[i][j]);
    }
    __syncthreads();
  }
#pragma unroll
  for (int i = 0; i < 8; ++i) {
    int m = m0 + tm + i;
#pragma unroll
    for (int j4 = 0; j4 < 8; j4 += 4) {
      int n = n0 + tn + j4;
      if (n + 4 <= N) {   // N is always a multiple of 4 here
        float4 v = make_float4(acc[i][j4], acc[i][j4 + 1], acc[i][j4 + 2], acc[i][j4 + 3]);
        *reinterpret_cast<float4*>(&C[(size_t)m * ldc + n]) = v;
      }
    }
  }
}

// ===================== depthwise causal conv, 4 taps =====================
// xh[m][ch] = cb[ch] + sum_j cw[ch][j] * xw[m-3+j][ch]   (zero-pad within sequence)
__global__ __launch_bounds__(256) void conv_kernel(
    const float* __restrict__ xw,   // [M][E_] (reads first 1024 cols)
    const float* __restrict__ cw,   // [1024][4]
    const float* __restrict__ cb,   // [1024]
    float* __restrict__ xh)         // [M][1024]
{
  int idx = blockIdx.x * 256 + threadIdx.x;   // over M*256
  int c4  = (idx & 255) << 2;
  int m   = idx >> 8;
  int s   = m & (S_ - 1);
  float4 a = *reinterpret_cast<const float4*>(&cb[c4]);
#pragma unroll
  for (int j = 0; j < 4; ++j) {
    int sp = s - 3 + j;
    if (sp >= 0) {
      float4 v = *reinterpret_cast<const float4*>(&xw[(size_t)(m - 3 + j) * E_ + c4]);
      a.x = fmaf(cw[(c4 + 0) * 4 + j], v.x, a.x);
      a.y = fmaf(cw[(c4 + 1) * 4 + j], v.y, a.y);
      a.z = fmaf(cw[(c4 + 2) * 4 + j], v.z, a.z);
      a.w = fmaf(cw[(c4 + 3) * 4 + j], v.w, a.w);
    }
  }
  *reinterpret_cast<float4*>(&xh[(size_t)m * DM + c4]) = a;
}

// ===================== per-(b,h) within-chunk cumsum of A =====================
__global__ __launch_bounds__(64) void scan_kernel(
    const float* __restrict__ xw,     // [M][E_], w at col 1024+h
    const float* __restrict__ w_base, // [16]
    float* __restrict__ Acum,         // [BH][NC][CH]
    float* __restrict__ acbuf)        // [BH][NC]  (chunk sums)
{
  int bh = blockIdx.x;
  int b  = bh >> 4;
  int h  = bh & 15;
  int lane = threadIdx.x;
  float wb = w_base[h];
  for (int c = 0; c < NC; ++c) {
    int s = c * CH + lane;
    float a = xw[(size_t)(b * S_ + s) * E_ + 1024 + h] * wb;
#pragma unroll
    for (int off = 1; off < 64; off <<= 1) {
      float v = __shfl_up(a, off);
      if (lane >= off) a += v;
    }
    Acum[((size_t)bh * NC + c) * CH + lane] = a;
    if (lane == 63) acbuf[(size_t)bh * NC + c] = a;
  }
}

// ===================== per-(b,h,c): L matrix, Y_diag, norm_diag, chunk states =====================
__global__ __launch_bounds__(256) void chunk_kernel(
    const float* __restrict__ xh,    // [M][1024]
    const float* __restrict__ Acum,  // [BH][NC][CH]
    float* __restrict__ ybuf,        // [M][1024]  (Y_diag out)
    float* __restrict__ normd,       // [BH][NC][CH]
    float* __restrict__ states,      // [BH][NC][DN]
    float* __restrict__ ndbuf)       // [BH][NC]
{
  int bi = blockIdx.x;               // b*1024 + h*64 + c
  int c  = bi & 63;
  int h  = (bi >> 6) & 15;
  int b  = bi >> 10;
  int bh = b * 16 + h;
  int t  = threadIdx.x;
  __shared__ float pc[CH], m1s[CH], dsv[CH];
  __shared__ float xs[CH][DN + 4];   // stride 68: float4-aligned, conflict-light
  __shared__ float Ls[CH][CH + 1];   // stride 65: odd stride for scalar reads
  size_t m0 = (size_t)b * S_ + (size_t)c * CH;
  size_t abase = ((size_t)bh * NC + c) * CH;

  if (t < 64) {
    float p = Acum[abase + t];
    pc[t] = p;
    float rmin = p;
#pragma unroll
    for (int off = 1; off < 64; off <<= 1) {
      float v = __shfl_up(rmin, off);
      if (t >= off) rmin = fminf(rmin, v);
    }
    m1s[t] = p - rmin;                       // rowmax of segsum row t
    float minall = __shfl(rmin, 63);         // min over whole chunk
    dsv[t] = __expf(minall - p);             // decay_states (max-subtracted)
  }
  // load x tile (coalesced)
  {
    int n  = t & 63;
    int r0 = t >> 6;
#pragma unroll
    for (int r = 0; r < 16; ++r) {
      int l = r0 + r * 4;
      xs[l][n] = xh[(m0 + l) * DM + h * DN + n];
    }
  }
  __syncthreads();
  // L[l][s] = exp(pc[l]-pc[s]-m1[l]) for s<=l else 0
  {
    int s  = t & 63;
    int r0 = t >> 6;
#pragma unroll
    for (int r = 0; r < 16; ++r) {
      int l = r0 + r * 4;
      Ls[l][s] = (s <= l) ? __expf(pc[l] - pc[s] - m1s[l]) : 0.f;
    }
  }
  __syncthreads();
  // Y_diag = L @ x ; norm_diag = row-sum(L). Thread: 4 l rows x 4 n cols.
  {
    int ngrp = t & 15;
    int lgrp = t >> 4;
    int n4   = ngrp * 4;
    int lb   = lgrp * 4;
    float4 acc[4];
    float  accn[4];
#pragma unroll
    for (int i = 0; i < 4; ++i) { acc[i] = make_float4(0.f, 0.f, 0.f, 0.f); accn[i] = 0.f; }
    for (int s = 0; s < 64; ++s) {
      float4 xv = *reinterpret_cast<const float4*>(&xs[s][n4]);
#pragma unroll
      for (int i = 0; i < 4; ++i) {
        float lv = Ls[lb + i][s];
        acc[i].x = fmaf(lv, xv.x, acc[i].x);
        acc[i].y = fmaf(lv, xv.y, acc[i].y);
        acc[i].z = fmaf(lv, xv.z, acc[i].z);
        acc[i].w = fmaf(lv, xv.w, acc[i].w);
        accn[i] += lv;
      }
    }
#pragma unroll
    for (int i = 0; i < 4; ++i) {
      *reinterpret_cast<float4*>(&ybuf[(m0 + lb + i) * DM + h * DN + n4]) = acc[i];
      if (ngrp == 0) normd[abase + lb + i] = accn[i];
    }
  }
  // states[n] = sum_l dsv[l]*x[l][n]; nd = sum_l dsv[l]
  if (t < 64) {
    float acc = 0.f;
    for (int s = 0; s < 64; ++s) acc = fmaf(dsv[s], xs[s][t], acc);
    states[((size_t)bh * NC + c) * DN + t] = acc;
    float v = dsv[t];
#pragma unroll
    for (int off = 32; off >= 1; off >>= 1) v += __shfl_down(v, off);
    if (t == 0) ndbuf[(size_t)bh * NC + c] = v;
  }
}

// ===================== inter-chunk propagation (65x65 decay_chunk) =====================
__global__ __launch_bounds__(256) void interchunk_kernel(
    const float* __restrict__ acbuf,   // [BH][NC]
    const float* __restrict__ states,  // [BH][NC][DN]
    const float* __restrict__ ndbuf,   // [BH][NC]
    float* __restrict__ nstates,       // [BH][NC][DN]
    float* __restrict__ nndbuf)        // [BH][NC]
{
  int bh = blockIdx.x;
  int t  = threadIdx.x;
  __shared__ float Ssum[NC], minP[NC], ndl[NC];
  if (t < 64) {
    float ac = acbuf[(size_t)bh * NC + t];
    float S = ac;
#pragma unroll
    for (int off = 1; off < 64; off <<= 1) {
      float v = __shfl_up(S, off);
      if (t >= off) S += v;
    }
    float Pc = S - ac;          // exclusive prefix sum
    float mp = Pc;
#pragma unroll
    for (int off = 1; off < 64; off <<= 1) {
      float v = __shfl_up(mp, off);
      if (t >= off) mp = fminf(mp, v);
    }
    Ssum[t] = S;
    minP[t] = mp;
    ndl[t]  = ndbuf[(size_t)bh * NC + t];
  }
  __syncthreads();
  int n  = t & 63;
  int r0 = t >> 6;
  for (int r = 0; r < 16; ++r) {
    int z = r0 + r * 4;
    float mpz = minP[z];
    float acc = 0.f;
    for (int j = 0; j < z; ++j) {
      float e = __expf(mpz - Ssum[j]);
      acc = fmaf(e, states[((size_t)bh * NC + j) * DN + n], acc);
    }
    nstates[((size_t)bh * NC + z) * DN + n] = acc;
  }
  if (t < 64) {
    int z = t;
    float mpz = minP[z];
    float acc = 0.f;
    for (int j = 0; j < z; ++j) acc = fmaf(__expf(mpz - Ssum[j]), ndl[j], acc);
    nndbuf[(size_t)bh * NC + z] = acc;
  }
}

// ===================== final: y = (Y_diag + states_off*sdo) / (norm_diag + nd_off*sdo) =====================
__global__ __launch_bounds__(256) void final_kernel(
    const float* __restrict__ Acum,
    const float* __restrict__ normd,
    const float* __restrict__ nstates,
    const float* __restrict__ nndbuf,
    float* __restrict__ ybuf)
{
  int bi = blockIdx.x;
  int c  = bi & 63;
  int h  = (bi >> 6) & 15;
  int b  = bi >> 10;
  int bh = b * 16 + h;
  int t  = threadIdx.x;
  __shared__ float sdo[CH], nrm[CH], sto[DN];
  __shared__ float ndo_s;
  size_t abase = ((size_t)bh * NC + c) * CH;
  if (t < 64) {
    float p = Acum[abase + t];
    float m3 = p;
#pragma unroll
    for (int off = 32; off >= 1; off >>= 1) m3 = fmaxf(m3, __shfl_down(m3, off));
    m3 = __shfl(m3, 0);
    sdo[t] = __expf(p - m3);
    nrm[t] = normd[abase + t];
    sto[t] = nstates[((size_t)bh * NC + c) * DN + t];
    if (t == 0) ndo_s = nndbuf[(size_t)bh * NC + c];
  }
  __syncthreads();
  size_t m0 = (size_t)b * S_ + (size_t)c * CH;
  int n  = t & 63;
  int r0 = t >> 6;
  float ndo = ndo_s;
#pragma unroll
  for (int r = 0; r < 16; ++r) {
    int l = r0 + r * 4;
    size_t a = (m0 + l) * DM + h * DN + n;
    float yd = ybuf[a];
    float sd = sdo[l];
    ybuf[a] = (yd + sto[n] * sd) / (nrm[l] + ndo * sd);
  }
}

// ===================== launch =====================
extern "C" void kernel_launch(void* const* d_in, const int* in_sizes, int n_in,
                              void* d_out, int out_size, void* d_ws, size_t ws_size,
                              hipStream_t stream) {
  const float* x          = (const float*)d_in[0];
  const float* in_proj_w  = (const float*)d_in[1];
  const float* conv_w     = (const float*)d_in[2];
  const float* conv_b     = (const float*)d_in[3];
  const float* w_base     = (const float*)d_in[4];
  const float* out_proj_w = (const float*)d_in[5];
  float* out = (float*)d_out;
  char* ws = (char*)d_ws;
  const int M = B_ * S_;

  // workspace layout (total ~279 MB)
  float* xw      = (float*)(ws);                  // [M][1040]  (also reused as ybuf)
  float* xh      = (float*)(ws + 136314880);      // [M][1024]
  float* Acum    = (float*)(ws + 270532608);      // [BH][64][64]
  float* acbuf   = (float*)(ws + 272629760);      // [BH][64]
  float* normd   = (float*)(ws + 272662528);      // [BH][64][64]
  float* states  = (float*)(ws + 274759680);      // [BH][64][64]
  float* ndbuf   = (float*)(ws + 276856832);      // [BH][64]
  float* nstates = (float*)(ws + 276889600);      // [BH][64][64]
  float* nndbuf  = (float*)(ws + 278986752);      // [BH][64]
  float* ybuf    = xw;                            // reuse: xi dead after conv

  dim3 g1((E_ + BN - 1) / BN, M / BM);            // 9 x 256
  sgemm_abt<<<g1, 256, 0, stream>>>(x, DM, in_proj_w, DM, xw, E_, M, E_, DM);
  conv_kernel<<<M, 256, 0, stream>>>(xw, conv_w, conv_b, xh);
  scan_kernel<<<128, 64, 0, stream>>>(xw, w_base, Acum, acbuf);
  chunk_kernel<<<8192, 256, 0, stream>>>(xh, Acum, ybuf, normd, states, ndbuf);
  interchunk_kernel<<<128, 256, 0, stream>>>(acbuf, states, ndbuf, nstates, nndbuf);
  final_kernel<<<8192, 256, 0, stream>>>(Acum, normd, nstates, nndbuf, ybuf);
  dim3 g2(DM / BN, M / BM);                       // 8 x 256
  sgemm_abt<<<g2, 256, 0, stream>>>(ybuf, DM, out_proj_w, DM, out, DM, M, DM, DM);
}

// Round 2
// 844.248 us; speedup vs baseline: 2.4655x; 2.4655x over previous
//
#include <hip/hip_runtime.h>
#include <hip/hip_bf16.h>
#include <cstdint>

#define B_ 8
#define S_ 4096
#define DM 1024
#define H_ 16
#define DN 64      // head dim
#define CH 64      // chunk length
#define NC 64      // chunks per sequence

typedef unsigned short u16;
typedef u16 u16x8 __attribute__((ext_vector_type(8)));
typedef u16 u16x4 __attribute__((ext_vector_type(4)));
typedef float f32x4 __attribute__((ext_vector_type(4)));
typedef __bf16 bf16x8 __attribute__((ext_vector_type(8)));

__device__ __forceinline__ float bf2f(u16 u) { return __uint_as_float(((unsigned)u) << 16); }
__device__ __forceinline__ u16 f2bf(float f) { __bf16 h = (__bf16)f; return __builtin_bit_cast(u16, h); }

#define GLOAD16(gp, lp) \
  __builtin_amdgcn_global_load_lds((__attribute__((address_space(1))) const void*)(gp), \
                                   (__attribute__((address_space(3))) void*)(lp), 16, 0, 0)

// ===================== bf16 MFMA GEMM: C[m][n] = sum_k A[m][k]*B[n][k] =====================
// 128x128 tile, BK=64, 4 waves (2x2), each wave 64x64 out (4x4 frags of 16x16).
// LDS layout: cell(kg, row) = [kg][row][8 bf16], kg = k/8 within tile. Conflict-light,
// and global_load_lds-compatible (linear dest = cell index * 16B).
template<int MODE>  // 0: fp32 out, 1: bf16 out
__global__ __launch_bounds__(256, 2) void bgemm(
    const u16* __restrict__ A, const u16* __restrict__ Bw,
    void* __restrict__ Cout, int K)
{
  __shared__ u16 ldsA[8 * 128 * 8];
  __shared__ u16 ldsB[8 * 128 * 8];
  const int m0 = blockIdx.y * 128;
  const int n0 = blockIdx.x * 128;
  const int t  = threadIdx.x;
  const int l  = t & 63;
  const int wid = t >> 6;
  const int wr = wid >> 1, wc = wid & 1;
  const int lr = l & 15, lk = l >> 4;

  f32x4 acc[4][4];
#pragma unroll
  for (int i = 0; i < 4; ++i)
#pragma unroll
    for (int j = 0; j < 4; ++j) acc[i][j] = (f32x4){0.f, 0.f, 0.f, 0.f};

  int cm[4], ck[4];
#pragma unroll
  for (int j = 0; j < 4; ++j) { int c = j * 256 + t; ck[j] = c >> 7; cm[j] = c & 127; }

  const int nkt = K >> 6;
  for (int kt = 0; kt < nkt; ++kt) {
#pragma unroll
    for (int j = 0; j < 4; ++j) {
      const u16* ga = A + (size_t)(m0 + cm[j]) * K + kt * 64 + ck[j] * 8;
      GLOAD16(ga, &ldsA[(j * 256 + t) * 8]);
    }
#pragma unroll
    for (int j = 0; j < 4; ++j) {
      const u16* gb = Bw + (size_t)(n0 + cm[j]) * K + kt * 64 + ck[j] * 8;
      GLOAD16(gb, &ldsB[(j * 256 + t) * 8]);
    }
    __syncthreads();   // compiler drains vmcnt before barrier
#pragma unroll
    for (int ks = 0; ks < 2; ++ks) {
      bf16x8 af[4], bfr[4];
#pragma unroll
      for (int mf = 0; mf < 4; ++mf) {
        int cell = (ks * 4 + lk) * 128 + wr * 64 + mf * 16 + lr;
        af[mf] = *reinterpret_cast<const bf16x8*>(&ldsA[cell * 8]);
      }
#pragma unroll
      for (int nf = 0; nf < 4; ++nf) {
        int cell = (ks * 4 + lk) * 128 + wc * 64 + nf * 16 + lr;
        bfr[nf] = *reinterpret_cast<const bf16x8*>(&ldsB[cell * 8]);
      }
#pragma unroll
      for (int mf = 0; mf < 4; ++mf)
#pragma unroll
        for (int nf = 0; nf < 4; ++nf)
          acc[mf][nf] = __builtin_amdgcn_mfma_f32_16x16x32_bf16(af[mf], bfr[nf], acc[mf][nf], 0, 0, 0);
    }
    __syncthreads();
  }
  // epilogue: D mapping col=lane&15, row=(lane>>4)*4+reg  [m89-verified]
#pragma unroll
  for (int mf = 0; mf < 4; ++mf) {
#pragma unroll
    for (int nf = 0; nf < 4; ++nf) {
      int n = n0 + wc * 64 + nf * 16 + lr;
      int mbase = m0 + wr * 64 + mf * 16 + lk * 4;
#pragma unroll
      for (int r = 0; r < 4; ++r) {
        if (MODE == 0) ((float*)Cout)[(size_t)(mbase + r) * 1024 + n] = acc[mf][nf][r];
        else           ((u16*)Cout)[(size_t)(mbase + r) * 1024 + n] = f2bf(acc[mf][nf][r]);
      }
    }
  }
}

// ===================== fp32 -> bf16 convert =====================
__global__ __launch_bounds__(256) void cvt32to16(const float* __restrict__ in, u16* __restrict__ out)
{
  size_t i = ((size_t)blockIdx.x * 256 + threadIdx.x) * 8;
  f32x4 a = *reinterpret_cast<const f32x4*>(&in[i]);
  f32x4 b = *reinterpret_cast<const f32x4*>(&in[i + 4]);
  u16x8 o;
#pragma unroll
  for (int j = 0; j < 4; ++j) { o[j] = f2bf(a[j]); o[4 + j] = f2bf(b[j]); }
  *reinterpret_cast<u16x8*>(&out[i]) = o;
}

// ===================== fp32 GEMM for the 16 w columns (precision-critical) =====================
// wbuf[m][h] = dot(x[m][:], in_proj_w[1024+h][:])  in full fp32
__global__ __launch_bounds__(256) void wgemm(
    const float* __restrict__ x, const float* __restrict__ ipw, float* __restrict__ wbuf)
{
  const int m0 = blockIdx.x * 64;
  const int t = threadIdx.x;
  const int h = t & 15;
  const int r = t >> 4;
  const f32x4* wp = reinterpret_cast<const f32x4*>(ipw + (size_t)(1024 + h) * 1024);
  f32x4 acc[4];
#pragma unroll
  for (int i = 0; i < 4; ++i) acc[i] = (f32x4){0.f, 0.f, 0.f, 0.f};
  for (int k4 = 0; k4 < 256; ++k4) {
    f32x4 wv = wp[k4];
#pragma unroll
    for (int rb = 0; rb < 4; ++rb) {
      f32x4 xv = *reinterpret_cast<const f32x4*>(&x[(size_t)(m0 + rb * 16 + r) * 1024 + k4 * 4]);
      acc[rb].x = fmaf(xv.x, wv.x, acc[rb].x);
      acc[rb].y = fmaf(xv.y, wv.y, acc[rb].y);
      acc[rb].z = fmaf(xv.z, wv.z, acc[rb].z);
      acc[rb].w = fmaf(xv.w, wv.w, acc[rb].w);
    }
  }
#pragma unroll
  for (int rb = 0; rb < 4; ++rb)
    wbuf[(size_t)(m0 + rb * 16 + r) * 16 + h] = (acc[rb].x + acc[rb].y) + (acc[rb].z + acc[rb].w);
}

// ===================== depthwise causal conv, 4 taps, bf16 in/out =====================
__global__ __launch_bounds__(256) void conv_kernel(
    const u16* __restrict__ xi, const float* __restrict__ cw,
    const float* __restrict__ cb, u16* __restrict__ xh)
{
  int idx = blockIdx.x * 256 + threadIdx.x;   // over M*128
  int m  = idx >> 7;
  int c8 = (idx & 127) << 3;
  int s  = m & (S_ - 1);
  float acc[8];
#pragma unroll
  for (int j = 0; j < 8; ++j) acc[j] = cb[c8 + j];
#pragma unroll
  for (int j = 0; j < 4; ++j) {
    int sp = s - 3 + j;
    if (sp >= 0) {
      u16x8 v = *reinterpret_cast<const u16x8*>(&xi[(size_t)(m - 3 + j) * DM + c8]);
#pragma unroll
      for (int jj = 0; jj < 8; ++jj)
        acc[jj] = fmaf(cw[(c8 + jj) * 4 + j], bf2f(v[jj]), acc[jj]);
    }
  }
  u16x8 o;
#pragma unroll
  for (int jj = 0; jj < 8; ++jj) o[jj] = f2bf(acc[jj]);
  *reinterpret_cast<u16x8*>(&xh[(size_t)m * DM + c8]) = o;
}

// ===================== per-(b,h,c): cumsum, L matrix, Y_diag, norm_diag, chunk states =====================
__global__ __launch_bounds__(256) void chunk_kernel(
    const u16* __restrict__ xh, const float* __restrict__ wbuf, const float* __restrict__ w_base,
    u16* __restrict__ ybuf, float* __restrict__ Acum, float* __restrict__ acbuf,
    float* __restrict__ normd, float* __restrict__ states, float* __restrict__ ndbuf)
{
  int bi = blockIdx.x;               // b*1024 + h*64 + c
  int c  = bi & 63;
  int h  = (bi >> 6) & 15;
  int b  = bi >> 10;
  int bh = b * 16 + h;
  int t  = threadIdx.x;
  __shared__ float pc[CH], m1s[CH], dsv[CH];
  __shared__ float xs[CH][DN + 4];
  __shared__ float Ls[CH][CH + 1];
  size_t m0 = (size_t)b * S_ + (size_t)c * CH;
  size_t abase = ((size_t)bh * NC + c) * CH;

  if (t < 64) {
    float p = wbuf[(m0 + t) * 16 + h] * w_base[h];
#pragma unroll
    for (int off = 1; off < 64; off <<= 1) {
      float v = __shfl_up(p, off);
      if (t >= off) p += v;
    }
    Acum[abase + t] = p;
    if (t == 63) acbuf[(size_t)bh * NC + c] = p;
    pc[t] = p;
    float rmin = p;
#pragma unroll
    for (int off = 1; off < 64; off <<= 1) {
      float v = __shfl_up(rmin, off);
      if (t >= off) rmin = fminf(rmin, v);
    }
    m1s[t] = p - rmin;                       // rowmax of segsum row t
    float minall = __shfl(rmin, 63);
    dsv[t] = __expf(minall - p);             // decay_states (max-subtracted)
  }
  // load x tile (bf16 -> fp32 LDS)
  {
    int g  = t & 7;
    int l0 = t >> 3;
    for (int li = l0; li < 64; li += 32) {
      u16x8 v = *reinterpret_cast<const u16x8*>(&xh[(m0 + li) * DM + h * DN + g * 8]);
#pragma unroll
      for (int jj = 0; jj < 8; ++jj) xs[li][g * 8 + jj] = bf2f(v[jj]);
    }
  }
  __syncthreads();
  {
    int s  = t & 63;
    int r0 = t >> 6;
#pragma unroll
    for (int r = 0; r < 16; ++r) {
      int l = r0 + r * 4;
      Ls[l][s] = (s <= l) ? __expf(pc[l] - pc[s] - m1s[l]) : 0.f;
    }
  }
  __syncthreads();
  // Y_diag = L @ x ; norm_diag = row-sum(L)
  {
    int ngrp = t & 15;
    int lgrp = t >> 4;
    int n4   = ngrp * 4;
    int lb   = lgrp * 4;
    float4 acc[4];
    float  accn[4];
#pragma unroll
    for (int i = 0; i < 4; ++i) { acc[i] = make_float4(0.f, 0.f, 0.f, 0.f); accn[i] = 0.f; }
    for (int s = 0; s < 64; ++s) {
      float4 xv = *reinterpret_cast<const float4*>(&xs[s][n4]);
#pragma unroll
      for (int i = 0; i < 4; ++i) {
        float lv = Ls[lb + i][s];
        acc[i].x = fmaf(lv, xv.x, acc[i].x);
        acc[i].y = fmaf(lv, xv.y, acc[i].y);
        acc[i].z = fmaf(lv, xv.z, acc[i].z);
        acc[i].w = fmaf(lv, xv.w, acc[i].w);
        accn[i] += lv;
      }
    }
#pragma unroll
    for (int i = 0; i < 4; ++i) {
      u16x4 o;
      o[0] = f2bf(acc[i].x); o[1] = f2bf(acc[i].y); o[2] = f2bf(acc[i].z); o[3] = f2bf(acc[i].w);
      *reinterpret_cast<u16x4*>(&ybuf[(m0 + lb + i) * DM + h * DN + n4]) = o;
      if (ngrp == 0) normd[abase + lb + i] = accn[i];
    }
  }
  // states[n] = sum_l dsv[l]*x[l][n]; nd = sum_l dsv[l]
  if (t < 64) {
    float acc = 0.f;
    for (int s = 0; s < 64; ++s) acc = fmaf(dsv[s], xs[s][t], acc);
    states[((size_t)bh * NC + c) * DN + t] = acc;
    float v = dsv[t];
#pragma unroll
    for (int off = 32; off >= 1; off >>= 1) v += __shfl_down(v, off);
    if (t == 0) ndbuf[(size_t)bh * NC + c] = v;
  }
}

// ===================== inter-chunk propagation =====================
__global__ __launch_bounds__(256) void interchunk_kernel(
    const float* __restrict__ acbuf, const float* __restrict__ states,
    const float* __restrict__ ndbuf, float* __restrict__ nstates, float* __restrict__ nndbuf)
{
  int bh = blockIdx.x;
  int t  = threadIdx.x;
  __shared__ float Ssum[NC], minP[NC], ndl[NC];
  if (t < 64) {
    float ac = acbuf[(size_t)bh * NC + t];
    float S = ac;
#pragma unroll
    for (int off = 1; off < 64; off <<= 1) {
      float v = __shfl_up(S, off);
      if (t >= off) S += v;
    }
    float Pc = S - ac;
    float mp = Pc;
#pragma unroll
    for (int off = 1; off < 64; off <<= 1) {
      float v = __shfl_up(mp, off);
      if (t >= off) mp = fminf(mp, v);
    }
    Ssum[t] = S;
    minP[t] = mp;
    ndl[t]  = ndbuf[(size_t)bh * NC + t];
  }
  __syncthreads();
  int n  = t & 63;
  int r0 = t >> 6;
  for (int r = 0; r < 16; ++r) {
    int z = r0 + r * 4;
    float mpz = minP[z];
    float acc = 0.f;
    for (int j = 0; j < z; ++j) {
      float e = __expf(mpz - Ssum[j]);
      acc = fmaf(e, states[((size_t)bh * NC + j) * DN + n], acc);
    }
    nstates[((size_t)bh * NC + z) * DN + n] = acc;
  }
  if (t < 64) {
    int z = t;
    float mpz = minP[z];
    float acc = 0.f;
    for (int j = 0; j < z; ++j) acc = fmaf(__expf(mpz - Ssum[j]), ndl[j], acc);
    nndbuf[(size_t)bh * NC + z] = acc;
  }
}

// ===================== final: y = (Y_diag + states_off*sdo) / (norm_diag + nd_off*sdo), bf16 in-place =====================
__global__ __launch_bounds__(256) void final_kernel(
    const float* __restrict__ Acum, const float* __restrict__ normd,
    const float* __restrict__ nstates, const float* __restrict__ nndbuf,
    u16* __restrict__ ybuf)
{
  int bi = blockIdx.x;
  int c  = bi & 63;
  int h  = (bi >> 6) & 15;
  int b  = bi >> 10;
  int bh = b * 16 + h;
  int t  = threadIdx.x;
  __shared__ float sdo[CH], nrm[CH], sto[DN];
  __shared__ float ndo_s;
  size_t abase = ((size_t)bh * NC + c) * CH;
  if (t < 64) {
    float p = Acum[abase + t];
    float m3 = p;
#pragma unroll
    for (int off = 32; off >= 1; off >>= 1) m3 = fmaxf(m3, __shfl_down(m3, off));
    m3 = __shfl(m3, 0);
    sdo[t] = __expf(p - m3);
    nrm[t] = normd[abase + t];
    sto[t] = nstates[((size_t)bh * NC + c) * DN + t];
    if (t == 0) ndo_s = nndbuf[(size_t)bh * NC + c];
  }
  __syncthreads();
  size_t m0 = (size_t)b * S_ + (size_t)c * CH;
  int g  = t & 7;
  int l0 = t >> 3;
  float ndo = ndo_s;
  for (int li = l0; li < 64; li += 32) {
    size_t a = (m0 + li) * DM + h * DN + g * 8;
    u16x8 v = *reinterpret_cast<u16x8*>(&ybuf[a]);
    float sd = sdo[li];
    float rec = 1.f / (nrm[li] + ndo * sd);
    u16x8 o;
#pragma unroll
    for (int jj = 0; jj < 8; ++jj) {
      float yd = bf2f(v[jj]);
      o[jj] = f2bf((yd + sto[g * 8 + jj] * sd) * rec);
    }
    *reinterpret_cast<u16x8*>(&ybuf[a]) = o;
  }
}

// ===================== launch =====================
extern "C" void kernel_launch(void* const* d_in, const int* in_sizes, int n_in,
                              void* d_out, int out_size, void* d_ws, size_t ws_size,
                              hipStream_t stream) {
  const float* x          = (const float*)d_in[0];
  const float* in_proj_w  = (const float*)d_in[1];
  const float* conv_w     = (const float*)d_in[2];
  const float* conv_b     = (const float*)d_in[3];
  const float* w_base     = (const float*)d_in[4];
  const float* out_proj_w = (const float*)d_in[5];
  float* out = (float*)d_out;
  char* ws = (char*)d_ws;
  const int M = B_ * S_;

  // workspace layout (~216 MB)
  u16*   wbf_in  = (u16*)  (ws + 0);
  u16*   wbf_out = (u16*)  (ws + 2097152);
  float* wbuf    = (float*)(ws + 4194304);
  float* Acum    = (float*)(ws + 6291456);
  float* acbuf   = (float*)(ws + 8388608);
  float* normd   = (float*)(ws + 8421376);
  float* states  = (float*)(ws + 10518528);
  float* ndbuf   = (float*)(ws + 12615680);
  float* nstates = (float*)(ws + 12648448);
  float* nndbuf  = (float*)(ws + 14745600);
  u16*   xbf     = (u16*)  (ws + 14778368);   // [M][1024] bf16 of x; later reused as ybuf
  u16*   xibf    = (u16*)  (ws + 81887232);   // [M][1024] bf16 xi (in_proj out)
  u16*   xh      = (u16*)  (ws + 148996096);  // [M][1024] bf16 conv out
  u16*   ybuf    = xbf;                       // xbf dead after bgemm1

  cvt32to16<<<16384, 256, 0, stream>>>(x, xbf);
  cvt32to16<<<512, 256, 0, stream>>>(in_proj_w, wbf_in);      // first 1024 rows
  cvt32to16<<<512, 256, 0, stream>>>(out_proj_w, wbf_out);
  bgemm<1><<<dim3(8, 256), 256, 0, stream>>>(xbf, wbf_in, (void*)xibf, DM);
  wgemm<<<512, 256, 0, stream>>>(x, in_proj_w, wbuf);
  conv_kernel<<<16384, 256, 0, stream>>>(xibf, conv_w, conv_b, xh);
  chunk_kernel<<<8192, 256, 0, stream>>>(xh, wbuf, w_base, ybuf, Acum, acbuf, normd, states, ndbuf);
  interchunk_kernel<<<128, 256, 0, stream>>>(acbuf, states, ndbuf, nstates, nndbuf);
  final_kernel<<<8192, 256, 0, stream>>>(Acum, normd, nstates, nndbuf, ybuf);
  bgemm<0><<<dim3(8, 256), 256, 0, stream>>>(ybuf, wbf_out, (void*)out, DM);
}

// Round 3
// 559.402 us; speedup vs baseline: 3.7209x; 1.5092x over previous
//
#include <hip/hip_runtime.h>
#include <hip/hip_bf16.h>
#include <cstdint>

#define B_ 8
#define S_ 4096
#define DM 1024
#define H_ 16
#define DN 64      // head dim
#define CH 64      // chunk length
#define NC 64      // chunks per sequence
#define M_ (B_ * S_)

typedef unsigned short u16;
typedef u16 u16x8 __attribute__((ext_vector_type(8)));
typedef u16 u16x4 __attribute__((ext_vector_type(4)));
typedef float f32x4 __attribute__((ext_vector_type(4)));
typedef __bf16 bf16x8 __attribute__((ext_vector_type(8)));

__device__ __forceinline__ float bf2f(u16 u) { return __uint_as_float(((unsigned)u) << 16); }
__device__ __forceinline__ u16 f2bf(float f) { __bf16 h = (__bf16)f; return __builtin_bit_cast(u16, h); }

#define GLOAD16(gp, lp) \
  __builtin_amdgcn_global_load_lds((__attribute__((address_space(1))) const void*)(gp), \
                                   (__attribute__((address_space(3))) void*)(lp), 16, 0, 0)

// ===================== bf16 MFMA GEMM: C[m][n] = sum_k A[m][k]*B[n][k] =====================
template<int MODE>  // 0: fp32 out, 1: bf16 out
__global__ __launch_bounds__(256, 2) void bgemm(
    const u16* __restrict__ A, const u16* __restrict__ Bw,
    void* __restrict__ Cout, int K)
{
  __shared__ u16 ldsA[8 * 128 * 8];
  __shared__ u16 ldsB[8 * 128 * 8];
  const int m0 = blockIdx.y * 128;
  const int n0 = blockIdx.x * 128;
  const int t  = threadIdx.x;
  const int l  = t & 63;
  const int wid = t >> 6;
  const int wr = wid >> 1, wc = wid & 1;
  const int lr = l & 15, lk = l >> 4;

  f32x4 acc[4][4];
#pragma unroll
  for (int i = 0; i < 4; ++i)
#pragma unroll
    for (int j = 0; j < 4; ++j) acc[i][j] = (f32x4){0.f, 0.f, 0.f, 0.f};

  int cm[4], ck[4];
#pragma unroll
  for (int j = 0; j < 4; ++j) { int c = j * 256 + t; ck[j] = c >> 7; cm[j] = c & 127; }

  const int nkt = K >> 6;
  for (int kt = 0; kt < nkt; ++kt) {
#pragma unroll
    for (int j = 0; j < 4; ++j) {
      const u16* ga = A + (size_t)(m0 + cm[j]) * K + kt * 64 + ck[j] * 8;
      GLOAD16(ga, &ldsA[(j * 256 + t) * 8]);
    }
#pragma unroll
    for (int j = 0; j < 4; ++j) {
      const u16* gb = Bw + (size_t)(n0 + cm[j]) * K + kt * 64 + ck[j] * 8;
      GLOAD16(gb, &ldsB[(j * 256 + t) * 8]);
    }
    __syncthreads();
#pragma unroll
    for (int ks = 0; ks < 2; ++ks) {
      bf16x8 af[4], bfr[4];
#pragma unroll
      for (int mf = 0; mf < 4; ++mf) {
        int cell = (ks * 4 + lk) * 128 + wr * 64 + mf * 16 + lr;
        af[mf] = *reinterpret_cast<const bf16x8*>(&ldsA[cell * 8]);
      }
#pragma unroll
      for (int nf = 0; nf < 4; ++nf) {
        int cell = (ks * 4 + lk) * 128 + wc * 64 + nf * 16 + lr;
        bfr[nf] = *reinterpret_cast<const bf16x8*>(&ldsB[cell * 8]);
      }
#pragma unroll
      for (int mf = 0; mf < 4; ++mf)
#pragma unroll
        for (int nf = 0; nf < 4; ++nf)
          acc[mf][nf] = __builtin_amdgcn_mfma_f32_16x16x32_bf16(af[mf], bfr[nf], acc[mf][nf], 0, 0, 0);
    }
    __syncthreads();
  }
#pragma unroll
  for (int mf = 0; mf < 4; ++mf) {
#pragma unroll
    for (int nf = 0; nf < 4; ++nf) {
      int n = n0 + wc * 64 + nf * 16 + lr;
      int mbase = m0 + wr * 64 + mf * 16 + lk * 4;
#pragma unroll
      for (int r = 0; r < 4; ++r) {
        if (MODE == 0) ((float*)Cout)[(size_t)(mbase + r) * 1024 + n] = acc[mf][nf][r];
        else           ((u16*)Cout)[(size_t)(mbase + r) * 1024 + n] = f2bf(acc[mf][nf][r]);
      }
    }
  }
}

// ===================== fp32 -> bf16 convert =====================
__global__ __launch_bounds__(256) void cvt32to16(const float* __restrict__ in, u16* __restrict__ out)
{
  size_t i = ((size_t)blockIdx.x * 256 + threadIdx.x) * 8;
  f32x4 a = *reinterpret_cast<const f32x4*>(&in[i]);
  f32x4 b = *reinterpret_cast<const f32x4*>(&in[i + 4]);
  u16x8 o;
#pragma unroll
  for (int j = 0; j < 4; ++j) { o[j] = f2bf(a[j]); o[4 + j] = f2bf(b[j]); }
  *reinterpret_cast<u16x8*>(&out[i]) = o;
}

// ===================== fp32 GEMM for the 16 w columns (precision-critical) =====================
// wbufT[h][m] = dot(x[m][:], in_proj_w[1024+h][:])  in full fp32, transposed store
__global__ __launch_bounds__(256) void wgemm(
    const float* __restrict__ x, const float* __restrict__ ipw, float* __restrict__ wbufT)
{
  const int m0 = blockIdx.x * 64;
  const int t = threadIdx.x;
  const int h = t & 15;
  const int r = t >> 4;
  const f32x4* wp = reinterpret_cast<const f32x4*>(ipw + (size_t)(1024 + h) * 1024);
  f32x4 acc[4];
#pragma unroll
  for (int i = 0; i < 4; ++i) acc[i] = (f32x4){0.f, 0.f, 0.f, 0.f};
  for (int k4 = 0; k4 < 256; ++k4) {
    f32x4 wv = wp[k4];
#pragma unroll
    for (int rb = 0; rb < 4; ++rb) {
      f32x4 xv = *reinterpret_cast<const f32x4*>(&x[(size_t)(m0 + rb * 16 + r) * 1024 + k4 * 4]);
      acc[rb].x = fmaf(xv.x, wv.x, acc[rb].x);
      acc[rb].y = fmaf(xv.y, wv.y, acc[rb].y);
      acc[rb].z = fmaf(xv.z, wv.z, acc[rb].z);
      acc[rb].w = fmaf(xv.w, wv.w, acc[rb].w);
    }
  }
#pragma unroll
  for (int rb = 0; rb < 4; ++rb)
    wbufT[(size_t)h * M_ + m0 + rb * 16 + r] = (acc[rb].x + acc[rb].y) + (acc[rb].z + acc[rb].w);
}

// ===================== fused per-(b,h,c): conv + cumsum + L(MFMA) + Y_diag + norm + states =====================
__global__ __launch_bounds__(256) void chunk_kernel(
    const u16* __restrict__ xi,        // [M][1024] bf16 (in_proj out, pre-conv)
    const float* __restrict__ cw, const float* __restrict__ cb,
    const float* __restrict__ wbufT, const float* __restrict__ w_base,
    u16* __restrict__ ybuf, float* __restrict__ Acum, float* __restrict__ acbuf,
    float* __restrict__ normd, float* __restrict__ states, float* __restrict__ ndbuf)
{
  int bi = blockIdx.x;               // b*1024 + h*64 + c
  int c  = bi & 63;
  int h  = (bi >> 6) & 15;
  int b  = bi >> 10;
  int bh = b * 16 + h;
  int t  = threadIdx.x;
  __shared__ u16 xis[67][64];        // raw xi tile (halo 3), bf16
  __shared__ u16 xsT[64][66];        // conv output, transposed [n][s], bf16
  __shared__ float pc[CH], m1s[CH], dsv[CH];
  __shared__ float wls[4][64];       // conv weights transposed [tap][ch]
  __shared__ float cbs[64];
  size_t m0 = (size_t)b * S_ + (size_t)c * CH;
  size_t abase = ((size_t)bh * NC + c) * CH;

  // conv weights: coalesced 1KB load, transposed into LDS
  wls[t & 3][t >> 2] = cw[(size_t)h * 256 + t];
  if (t < 64) cbs[t] = cb[h * 64 + t];

  // xi halo tile: rows hr=0..66 <-> global m0-3+hr (zeros before sequence start)
  {
    int g8  = t & 7;
    int hr0 = t >> 3;
    for (int hr = hr0; hr < 67; hr += 32) {
      u16x8 v = {0, 0, 0, 0, 0, 0, 0, 0};
      if (!(c == 0 && hr < 3))
        v = *reinterpret_cast<const u16x8*>(&xi[(m0 - 3 + hr) * DM + h * 64 + g8 * 8]);
      *reinterpret_cast<u16x8*>(&xis[hr][g8 * 8]) = v;
    }
  }

  // wave0: within-chunk cumsum of A, rowmax/min prefixes, decay_states
  if (t < 64) {
    float p = wbufT[(size_t)h * M_ + m0 + t] * w_base[h];
#pragma unroll
    for (int off = 1; off < 64; off <<= 1) {
      float v = __shfl_up(p, off);
      if (t >= off) p += v;
    }
    Acum[abase + t] = p;
    if (t == 63) acbuf[(size_t)bh * NC + c] = p;
    pc[t] = p;
    float rmin = p;
#pragma unroll
    for (int off = 1; off < 64; off <<= 1) {
      float v = __shfl_up(rmin, off);
      if (t >= off) rmin = fminf(rmin, v);
    }
    m1s[t] = p - rmin;
    float minall = __shfl(rmin, 63);
    dsv[t] = __expf(minall - p);
  }
  __syncthreads();

  // conv: thread owns channel n, 16 consecutive rows; sliding 4-tap window
  {
    int n  = t & 63;
    int lb = (t >> 6) * 16;
    float w0 = wls[0][n], w1 = wls[1][n], w2 = wls[2][n], w3 = wls[3][n];
    float bias = cbs[n];
    float a = bf2f(xis[lb + 0][n]);
    float bv = bf2f(xis[lb + 1][n]);
    float cv = bf2f(xis[lb + 2][n]);
    u16x8 o0, o1;
#pragma unroll
    for (int r = 0; r < 16; ++r) {
      float dv = bf2f(xis[lb + r + 3][n]);
      float s = fmaf(w3, dv, fmaf(w2, cv, fmaf(w1, bv, fmaf(w0, a, bias))));
      if (r < 8) o0[r] = f2bf(s); else o1[r - 8] = f2bf(s);
      a = bv; bv = cv; cv = dv;
    }
    *reinterpret_cast<u16x8*>(&xsT[n][lb]) = o0;
    *reinterpret_cast<u16x8*>(&xsT[n][lb + 8]) = o1;
  }
  __syncthreads();

  // MFMA phase: wave w owns output rows w*16..w*16+15.
  // A-frag (L): lane holds row=w*16+(l&15), k=(ks*32)+(l>>4)*8+j  [round-2-verified layout]
  {
    int w = t >> 6, l = t & 63;
    int lr = l & 15, lk = l >> 4;
    int row = w * 16 + lr;
    float pr = pc[row], m1r = m1s[row];
    bf16x8 afr[2];
    float np = 0.f;
#pragma unroll
    for (int ks = 0; ks < 2; ++ks) {
      int sbase = ks * 32 + lk * 8;
      u16x8 av;
#pragma unroll
      for (int j = 0; j < 8; ++j) {
        int s = sbase + j;
        float L = (s <= row) ? __expf(pr - pc[s] - m1r) : 0.f;
        np += L;
        av[j] = f2bf(L);
      }
      afr[ks] = __builtin_bit_cast(bf16x8, av);
    }
    np += __shfl_xor(np, 16);
    np += __shfl_xor(np, 32);
    if (lk == 0) normd[abase + row] = np;

    f32x4 acc[4];
#pragma unroll
    for (int nf = 0; nf < 4; ++nf) acc[nf] = (f32x4){0.f, 0.f, 0.f, 0.f};
#pragma unroll
    for (int ks = 0; ks < 2; ++ks)
#pragma unroll
      for (int nf = 0; nf < 4; ++nf) {
        bf16x8 bfr = *reinterpret_cast<const bf16x8*>(&xsT[nf * 16 + lr][ks * 32 + lk * 8]);
        acc[nf] = __builtin_amdgcn_mfma_f32_16x16x32_bf16(afr[ks], bfr, acc[nf], 0, 0, 0);
      }
    // C mapping: col=lane&15, row=(lane>>4)*4+reg
#pragma unroll
    for (int nf = 0; nf < 4; ++nf)
#pragma unroll
      for (int r = 0; r < 4; ++r)
        ybuf[(m0 + w * 16 + lk * 4 + r) * DM + h * 64 + nf * 16 + lr] = f2bf(acc[nf][r]);
  }

  // states + norm-decay sum (wave0)
  if (t < 64) {
    float acc = 0.f;
#pragma unroll
    for (int l8 = 0; l8 < 64; l8 += 8) {
      u16x8 xv = *reinterpret_cast<const u16x8*>(&xsT[t][l8]);
#pragma unroll
      for (int j = 0; j < 8; ++j) acc = fmaf(dsv[l8 + j], bf2f(xv[j]), acc);
    }
    states[((size_t)bh * NC + c) * DN + t] = acc;
    float v = dsv[t];
#pragma unroll
    for (int off = 32; off >= 1; off >>= 1) v += __shfl_down(v, off);
    if (t == 0) ndbuf[(size_t)bh * NC + c] = v;
  }
}

// ===================== inter-chunk propagation =====================
__global__ __launch_bounds__(256) void interchunk_kernel(
    const float* __restrict__ acbuf, const float* __restrict__ states,
    const float* __restrict__ ndbuf, float* __restrict__ nstates, float* __restrict__ nndbuf)
{
  int bh = blockIdx.x;
  int t  = threadIdx.x;
  __shared__ float Ssum[NC], minP[NC], ndl[NC];
  if (t < 64) {
    float ac = acbuf[(size_t)bh * NC + t];
    float S = ac;
#pragma unroll
    for (int off = 1; off < 64; off <<= 1) {
      float v = __shfl_up(S, off);
      if (t >= off) S += v;
    }
    float Pc = S - ac;
    float mp = Pc;
#pragma unroll
    for (int off = 1; off < 64; off <<= 1) {
      float v = __shfl_up(mp, off);
      if (t >= off) mp = fminf(mp, v);
    }
    Ssum[t] = S;
    minP[t] = mp;
    ndl[t]  = ndbuf[(size_t)bh * NC + t];
  }
  __syncthreads();
  int n  = t & 63;
  int r0 = t >> 6;
  for (int r = 0; r < 16; ++r) {
    int z = r0 + r * 4;
    float mpz = minP[z];
    float acc = 0.f;
    for (int j = 0; j < z; ++j) {
      float e = __expf(mpz - Ssum[j]);
      acc = fmaf(e, states[((size_t)bh * NC + j) * DN + n], acc);
    }
    nstates[((size_t)bh * NC + z) * DN + n] = acc;
  }
  if (t < 64) {
    int z = t;
    float mpz = minP[z];
    float acc = 0.f;
    for (int j = 0; j < z; ++j) acc = fmaf(__expf(mpz - Ssum[j]), ndl[j], acc);
    nndbuf[(size_t)bh * NC + z] = acc;
  }
}

// ===================== final: y = (Y_diag + states_off*sdo) / (norm_diag + nd_off*sdo) =====================
__global__ __launch_bounds__(256) void final_kernel(
    const float* __restrict__ Acum, const float* __restrict__ normd,
    const float* __restrict__ nstates, const float* __restrict__ nndbuf,
    u16* __restrict__ ybuf)
{
  int bi = blockIdx.x;
  int c  = bi & 63;
  int h  = (bi >> 6) & 15;
  int b  = bi >> 10;
  int bh = b * 16 + h;
  int t  = threadIdx.x;
  __shared__ float sdo[CH], nrm[CH], sto[DN];
  __shared__ float ndo_s;
  size_t abase = ((size_t)bh * NC + c) * CH;
  if (t < 64) {
    float p = Acum[abase + t];
    float m3 = p;
#pragma unroll
    for (int off = 32; off >= 1; off >>= 1) m3 = fmaxf(m3, __shfl_down(m3, off));
    m3 = __shfl(m3, 0);
    sdo[t] = __expf(p - m3);
    nrm[t] = normd[abase + t];
    sto[t] = nstates[((size_t)bh * NC + c) * DN + t];
    if (t == 0) ndo_s = nndbuf[(size_t)bh * NC + c];
  }
  __syncthreads();
  size_t m0 = (size_t)b * S_ + (size_t)c * CH;
  int g  = t & 7;
  int l0 = t >> 3;
  float ndo = ndo_s;
  for (int li = l0; li < 64; li += 32) {
    size_t a = (m0 + li) * DM + h * DN + g * 8;
    u16x8 v = *reinterpret_cast<u16x8*>(&ybuf[a]);
    float sd = sdo[li];
    float rec = 1.f / (nrm[li] + ndo * sd);
    u16x8 o;
#pragma unroll
    for (int jj = 0; jj < 8; ++jj) {
      float yd = bf2f(v[jj]);
      o[jj] = f2bf((yd + sto[g * 8 + jj] * sd) * rec);
    }
    *reinterpret_cast<u16x8*>(&ybuf[a]) = o;
  }
}

// ===================== launch =====================
extern "C" void kernel_launch(void* const* d_in, const int* in_sizes, int n_in,
                              void* d_out, int out_size, void* d_ws, size_t ws_size,
                              hipStream_t stream) {
  const float* x          = (const float*)d_in[0];
  const float* in_proj_w  = (const float*)d_in[1];
  const float* conv_w     = (const float*)d_in[2];
  const float* conv_b     = (const float*)d_in[3];
  const float* w_base     = (const float*)d_in[4];
  const float* out_proj_w = (const float*)d_in[5];
  float* out = (float*)d_out;
  char* ws = (char*)d_ws;

  // workspace layout (~146 MB)
  u16*   wbf_in  = (u16*)  (ws + 0);
  u16*   wbf_out = (u16*)  (ws + 2097152);
  float* wbufT   = (float*)(ws + 4194304);
  float* Acum    = (float*)(ws + 6291456);
  float* acbuf   = (float*)(ws + 8388608);
  float* normd   = (float*)(ws + 8421376);
  float* states  = (float*)(ws + 10518528);
  float* ndbuf   = (float*)(ws + 12615680);
  float* nstates = (float*)(ws + 12648448);
  float* nndbuf  = (float*)(ws + 14745600);
  u16*   xbf     = (u16*)  (ws + 14778368);   // [M][1024] bf16 of x; reused as ybuf
  u16*   xibf    = (u16*)  (ws + 81887232);   // [M][1024] bf16 xi (in_proj out)
  u16*   ybuf    = xbf;

  cvt32to16<<<16384, 256, 0, stream>>>(x, xbf);
  cvt32to16<<<512, 256, 0, stream>>>(in_proj_w, wbf_in);
  cvt32to16<<<512, 256, 0, stream>>>(out_proj_w, wbf_out);
  bgemm<1><<<dim3(8, 256), 256, 0, stream>>>(xbf, wbf_in, (void*)xibf, DM);
  wgemm<<<512, 256, 0, stream>>>(x, in_proj_w, wbufT);
  chunk_kernel<<<8192, 256, 0, stream>>>(xibf, conv_w, conv_b, wbufT, w_base,
                                         ybuf, Acum, acbuf, normd, states, ndbuf);
  interchunk_kernel<<<128, 256, 0, stream>>>(acbuf, states, ndbuf, nstates, nndbuf);
  final_kernel<<<8192, 256, 0, stream>>>(Acum, normd, nstates, nndbuf, ybuf);
  bgemm<0><<<dim3(8, 256), 256, 0, stream>>>(ybuf, wbf_out, (void*)out, DM);
}

// Round 4
// 551.043 us; speedup vs baseline: 3.7773x; 1.0152x over previous
//
#include <hip/hip_runtime.h>
#include <hip/hip_bf16.h>
#include <cstdint>

#define B_ 8
#define S_ 4096
#define DM 1024
#define H_ 16
#define DN 64      // head dim
#define CH 64      // chunk length
#define NC 64      // chunks per sequence
#define M_ (B_ * S_)

typedef unsigned short u16;
typedef u16 u16x8 __attribute__((ext_vector_type(8)));
typedef u16 u16x4 __attribute__((ext_vector_type(4)));
typedef float f32x4 __attribute__((ext_vector_type(4)));
typedef __bf16 bf16x8 __attribute__((ext_vector_type(8)));

__device__ __forceinline__ float bf2f(u16 u) { return __uint_as_float(((unsigned)u) << 16); }
__device__ __forceinline__ u16 f2bf(float f) { __bf16 h = (__bf16)f; return __builtin_bit_cast(u16, h); }

#define GLOAD16(gp, lp) \
  __builtin_amdgcn_global_load_lds((__attribute__((address_space(1))) const void*)(gp), \
                                   (__attribute__((address_space(3))) void*)(lp), 16, 0, 0)

// ===================== bf16 MFMA GEMM: C[m][n] = sum_k A[m][k]*B[n][k] =====================
// 128x128 tile, BK=64, 4 waves. 1-D grid of 2048 blocks with XCD-aware swizzle:
// XCD k (hw round-robin = orig%8) owns m-tiles [k*32, k*32+32), n-tiles cycling fast
// -> each A-panel fetched by exactly ONE XCD, B fully L2-resident (2 MB).
template<int MODE>  // 0: fp32 out, 1: bf16 out
__global__ __launch_bounds__(256, 4) void bgemm(
    const u16* __restrict__ A, const u16* __restrict__ Bw,
    void* __restrict__ Cout, int K)
{
  __shared__ u16 ldsA[8 * 128 * 8];
  __shared__ u16 ldsB[8 * 128 * 8];
  const int orig = blockIdx.x;
  const int swz  = (orig & 7) * 256 + (orig >> 3);   // bijective: 2048 % 8 == 0
  const int m0 = (swz >> 3) * 128;
  const int n0 = (swz & 7) * 128;
  const int t  = threadIdx.x;
  const int l  = t & 63;
  const int wid = t >> 6;
  const int wr = wid >> 1, wc = wid & 1;
  const int lr = l & 15, lk = l >> 4;

  f32x4 acc[4][4];
#pragma unroll
  for (int i = 0; i < 4; ++i)
#pragma unroll
    for (int j = 0; j < 4; ++j) acc[i][j] = (f32x4){0.f, 0.f, 0.f, 0.f};

  int cm[4], ck[4];
#pragma unroll
  for (int j = 0; j < 4; ++j) { int c = j * 256 + t; ck[j] = c >> 7; cm[j] = c & 127; }

  const int nkt = K >> 6;
  for (int kt = 0; kt < nkt; ++kt) {
#pragma unroll
    for (int j = 0; j < 4; ++j) {
      const u16* ga = A + (size_t)(m0 + cm[j]) * K + kt * 64 + ck[j] * 8;
      GLOAD16(ga, &ldsA[(j * 256 + t) * 8]);
    }
#pragma unroll
    for (int j = 0; j < 4; ++j) {
      const u16* gb = Bw + (size_t)(n0 + cm[j]) * K + kt * 64 + ck[j] * 8;
      GLOAD16(gb, &ldsB[(j * 256 + t) * 8]);
    }
    __syncthreads();
#pragma unroll
    for (int ks = 0; ks < 2; ++ks) {
      bf16x8 af[4], bfr[4];
#pragma unroll
      for (int mf = 0; mf < 4; ++mf) {
        int cell = (ks * 4 + lk) * 128 + wr * 64 + mf * 16 + lr;
        af[mf] = *reinterpret_cast<const bf16x8*>(&ldsA[cell * 8]);
      }
#pragma unroll
      for (int nf = 0; nf < 4; ++nf) {
        int cell = (ks * 4 + lk) * 128 + wc * 64 + nf * 16 + lr;
        bfr[nf] = *reinterpret_cast<const bf16x8*>(&ldsB[cell * 8]);
      }
#pragma unroll
      for (int mf = 0; mf < 4; ++mf)
#pragma unroll
        for (int nf = 0; nf < 4; ++nf)
          acc[mf][nf] = __builtin_amdgcn_mfma_f32_16x16x32_bf16(af[mf], bfr[nf], acc[mf][nf], 0, 0, 0);
    }
    __syncthreads();
  }
#pragma unroll
  for (int mf = 0; mf < 4; ++mf) {
#pragma unroll
    for (int nf = 0; nf < 4; ++nf) {
      int n = n0 + wc * 64 + nf * 16 + lr;
      int mbase = m0 + wr * 64 + mf * 16 + lk * 4;
#pragma unroll
      for (int r = 0; r < 4; ++r) {
        if (MODE == 0) ((float*)Cout)[(size_t)(mbase + r) * 1024 + n] = acc[mf][nf][r];
        else           ((u16*)Cout)[(size_t)(mbase + r) * 1024 + n] = f2bf(acc[mf][nf][r]);
      }
    }
  }
}

// ===================== fp32 -> bf16 convert (weights only) =====================
__global__ __launch_bounds__(256) void cvt32to16(const float* __restrict__ in, u16* __restrict__ out)
{
  size_t i = ((size_t)blockIdx.x * 256 + threadIdx.x) * 8;
  f32x4 a = *reinterpret_cast<const f32x4*>(&in[i]);
  f32x4 b = *reinterpret_cast<const f32x4*>(&in[i + 4]);
  u16x8 o;
#pragma unroll
  for (int j = 0; j < 4; ++j) { o[j] = f2bf(a[j]); o[4 + j] = f2bf(b[j]); }
  *reinterpret_cast<u16x8*>(&out[i]) = o;
}

// ===================== fp32 GEMM for the 16 w columns + fused x->bf16 =====================
// wbufT[h][m] = dot(x[m][:], in_proj_w[1024+h][:]) in fp32; also emits xbf (bf16 of x).
__global__ __launch_bounds__(256) void wgemm(
    const float* __restrict__ x, const float* __restrict__ ipw,
    float* __restrict__ wbufT, u16* __restrict__ xbf)
{
  const int m0 = blockIdx.x * 64;
  const int t = threadIdx.x;
  const int h = t & 15;
  const int r = t >> 4;
  const f32x4* wp = reinterpret_cast<const f32x4*>(ipw + (size_t)(1024 + h) * 1024);
  f32x4 acc[4];
#pragma unroll
  for (int i = 0; i < 4; ++i) acc[i] = (f32x4){0.f, 0.f, 0.f, 0.f};
  for (int k4 = 0; k4 < 256; ++k4) {
    f32x4 wv = wp[k4];
#pragma unroll
    for (int rb = 0; rb < 4; ++rb) {
      f32x4 xv = *reinterpret_cast<const f32x4*>(&x[(size_t)(m0 + rb * 16 + r) * 1024 + k4 * 4]);
      acc[rb].x = fmaf(xv.x, wv.x, acc[rb].x);
      acc[rb].y = fmaf(xv.y, wv.y, acc[rb].y);
      acc[rb].z = fmaf(xv.z, wv.z, acc[rb].z);
      acc[rb].w = fmaf(xv.w, wv.w, acc[rb].w);
    }
  }
#pragma unroll
  for (int rb = 0; rb < 4; ++rb)
    wbufT[(size_t)h * M_ + m0 + rb * 16 + r] = (acc[rb].x + acc[rb].y) + (acc[rb].z + acc[rb].w);
  // fused conversion: thread owns rows m0+rb*16+r, cols [h*64, h*64+64) — cache-hot
#pragma unroll
  for (int rb = 0; rb < 4; ++rb) {
    size_t row = (size_t)(m0 + rb * 16 + r) * 1024;
#pragma unroll
    for (int q = 0; q < 16; ++q) {
      f32x4 xv = *reinterpret_cast<const f32x4*>(&x[row + h * 64 + q * 4]);
      u16x4 o;
      o[0] = f2bf(xv.x); o[1] = f2bf(xv.y); o[2] = f2bf(xv.z); o[3] = f2bf(xv.w);
      *reinterpret_cast<u16x4*>(&xbf[row + h * 64 + q * 4]) = o;
    }
  }
}

// ===================== fused per-(b,h,c): conv + cumsum + L(MFMA) + Y_diag + norm + states =====================
__global__ __launch_bounds__(256) void chunk_kernel(
    const u16* __restrict__ xi,        // [M][1024] bf16 (in_proj out, pre-conv)
    const float* __restrict__ cw, const float* __restrict__ cb,
    const float* __restrict__ wbufT, const float* __restrict__ w_base,
    u16* __restrict__ ybuf, float* __restrict__ Acum, float* __restrict__ acbuf,
    float* __restrict__ normd, float* __restrict__ states, float* __restrict__ ndbuf)
{
  int bi = blockIdx.x;               // b*1024 + h*64 + c
  int c  = bi & 63;
  int h  = (bi >> 6) & 15;
  int b  = bi >> 10;
  int bh = b * 16 + h;
  int t  = threadIdx.x;
  __shared__ u16 xis[67][64];        // raw xi tile (halo 3), bf16
  __shared__ u16 xsT[64][66];        // conv output, transposed [n][s], bf16
  __shared__ float pc[CH], m1s[CH], dsv[CH];
  __shared__ float wls[4][64];       // conv weights transposed [tap][ch]
  __shared__ float cbs[64];
  size_t m0 = (size_t)b * S_ + (size_t)c * CH;
  size_t abase = ((size_t)bh * NC + c) * CH;

  wls[t & 3][t >> 2] = cw[(size_t)h * 256 + t];
  if (t < 64) cbs[t] = cb[h * 64 + t];

  {
    int g8  = t & 7;
    int hr0 = t >> 3;
    for (int hr = hr0; hr < 67; hr += 32) {
      u16x8 v = {0, 0, 0, 0, 0, 0, 0, 0};
      if (!(c == 0 && hr < 3))
        v = *reinterpret_cast<const u16x8*>(&xi[(m0 - 3 + hr) * DM + h * 64 + g8 * 8]);
      *reinterpret_cast<u16x8*>(&xis[hr][g8 * 8]) = v;
    }
  }

  if (t < 64) {
    float p = wbufT[(size_t)h * M_ + m0 + t] * w_base[h];
#pragma unroll
    for (int off = 1; off < 64; off <<= 1) {
      float v = __shfl_up(p, off);
      if (t >= off) p += v;
    }
    Acum[abase + t] = p;
    if (t == 63) acbuf[(size_t)bh * NC + c] = p;
    pc[t] = p;
    float rmin = p;
#pragma unroll
    for (int off = 1; off < 64; off <<= 1) {
      float v = __shfl_up(rmin, off);
      if (t >= off) rmin = fminf(rmin, v);
    }
    m1s[t] = p - rmin;
    float minall = __shfl(rmin, 63);
    dsv[t] = __expf(minall - p);
  }
  __syncthreads();

  // conv: thread owns channel n, 16 consecutive rows; sliding 4-tap window
  {
    int n  = t & 63;
    int lb = (t >> 6) * 16;
    float w0 = wls[0][n], w1 = wls[1][n], w2 = wls[2][n], w3 = wls[3][n];
    float bias = cbs[n];
    float a = bf2f(xis[lb + 0][n]);
    float bv = bf2f(xis[lb + 1][n]);
    float cv = bf2f(xis[lb + 2][n]);
    u16x8 o0, o1;
#pragma unroll
    for (int r = 0; r < 16; ++r) {
      float dv = bf2f(xis[lb + r + 3][n]);
      float s = fmaf(w3, dv, fmaf(w2, cv, fmaf(w1, bv, fmaf(w0, a, bias))));
      if (r < 8) o0[r] = f2bf(s); else o1[r - 8] = f2bf(s);
      a = bv; bv = cv; cv = dv;
    }
    *reinterpret_cast<u16x8*>(&xsT[n][lb]) = o0;
    *reinterpret_cast<u16x8*>(&xsT[n][lb + 8]) = o1;
  }
  __syncthreads();

  // MFMA phase: wave w owns output rows w*16..w*16+15.
  {
    int w = t >> 6, l = t & 63;
    int lr = l & 15, lk = l >> 4;
    int row = w * 16 + lr;
    float pr = pc[row], m1r = m1s[row];
    bf16x8 afr[2];
    float np = 0.f;
#pragma unroll
    for (int ks = 0; ks < 2; ++ks) {
      int sbase = ks * 32 + lk * 8;
      u16x8 av;
#pragma unroll
      for (int j = 0; j < 8; ++j) {
        int s = sbase + j;
        float L = (s <= row) ? __expf(pr - pc[s] - m1r) : 0.f;
        np += L;
        av[j] = f2bf(L);
      }
      afr[ks] = __builtin_bit_cast(bf16x8, av);
    }
    np += __shfl_xor(np, 16);
    np += __shfl_xor(np, 32);
    if (lk == 0) normd[abase + row] = np;

    f32x4 acc[4];
#pragma unroll
    for (int nf = 0; nf < 4; ++nf) acc[nf] = (f32x4){0.f, 0.f, 0.f, 0.f};
#pragma unroll
    for (int ks = 0; ks < 2; ++ks)
#pragma unroll
      for (int nf = 0; nf < 4; ++nf) {
        bf16x8 bfr = *reinterpret_cast<const bf16x8*>(&xsT[nf * 16 + lr][ks * 32 + lk * 8]);
        acc[nf] = __builtin_amdgcn_mfma_f32_16x16x32_bf16(afr[ks], bfr, acc[nf], 0, 0, 0);
      }
#pragma unroll
    for (int nf = 0; nf < 4; ++nf)
#pragma unroll
      for (int r = 0; r < 4; ++r)
        ybuf[(m0 + w * 16 + lk * 4 + r) * DM + h * 64 + nf * 16 + lr] = f2bf(acc[nf][r]);
  }

  if (t < 64) {
    float acc = 0.f;
#pragma unroll
    for (int l8 = 0; l8 < 64; l8 += 8) {
      u16x8 xv = *reinterpret_cast<const u16x8*>(&xsT[t][l8]);
#pragma unroll
      for (int j = 0; j < 8; ++j) acc = fmaf(dsv[l8 + j], bf2f(xv[j]), acc);
    }
    states[((size_t)bh * NC + c) * DN + t] = acc;
    float v = dsv[t];
#pragma unroll
    for (int off = 32; off >= 1; off >>= 1) v += __shfl_down(v, off);
    if (t == 0) ndbuf[(size_t)bh * NC + c] = v;
  }
}

// ===================== inter-chunk propagation =====================
__global__ __launch_bounds__(256) void interchunk_kernel(
    const float* __restrict__ acbuf, const float* __restrict__ states,
    const float* __restrict__ ndbuf, float* __restrict__ nstates, float* __restrict__ nndbuf)
{
  int bh = blockIdx.x;
  int t  = threadIdx.x;
  __shared__ float Ssum[NC], minP[NC], ndl[NC];
  if (t < 64) {
    float ac = acbuf[(size_t)bh * NC + t];
    float S = ac;
#pragma unroll
    for (int off = 1; off < 64; off <<= 1) {
      float v = __shfl_up(S, off);
      if (t >= off) S += v;
    }
    float Pc = S - ac;
    float mp = Pc;
#pragma unroll
    for (int off = 1; off < 64; off <<= 1) {
      float v = __shfl_up(mp, off);
      if (t >= off) mp = fminf(mp, v);
    }
    Ssum[t] = S;
    minP[t] = mp;
    ndl[t]  = ndbuf[(size_t)bh * NC + t];
  }
  __syncthreads();
  int n  = t & 63;
  int r0 = t >> 6;
  for (int r = 0; r < 16; ++r) {
    int z = r0 + r * 4;
    float mpz = minP[z];
    float acc = 0.f;
    for (int j = 0; j < z; ++j) {
      float e = __expf(mpz - Ssum[j]);
      acc = fmaf(e, states[((size_t)bh * NC + j) * DN + n], acc);
    }
    nstates[((size_t)bh * NC + z) * DN + n] = acc;
  }
  if (t < 64) {
    int z = t;
    float mpz = minP[z];
    float acc = 0.f;
    for (int j = 0; j < z; ++j) acc = fmaf(__expf(mpz - Ssum[j]), ndl[j], acc);
    nndbuf[(size_t)bh * NC + z] = acc;
  }
}

// ===================== final: y = (Y_diag + states_off*sdo) / (norm_diag + nd_off*sdo) =====================
__global__ __launch_bounds__(256) void final_kernel(
    const float* __restrict__ Acum, const float* __restrict__ normd,
    const float* __restrict__ nstates, const float* __restrict__ nndbuf,
    u16* __restrict__ ybuf)
{
  int bi = blockIdx.x;
  int c  = bi & 63;
  int h  = (bi >> 6) & 15;
  int b  = bi >> 10;
  int bh = b * 16 + h;
  int t  = threadIdx.x;
  __shared__ float sdo[CH], nrm[CH], sto[DN];
  __shared__ float ndo_s;
  size_t abase = ((size_t)bh * NC + c) * CH;
  if (t < 64) {
    float p = Acum[abase + t];
    float m3 = p;
#pragma unroll
    for (int off = 32; off >= 1; off >>= 1) m3 = fmaxf(m3, __shfl_down(m3, off));
    m3 = __shfl(m3, 0);
    sdo[t] = __expf(p - m3);
    nrm[t] = normd[abase + t];
    sto[t] = nstates[((size_t)bh * NC + c) * DN + t];
    if (t == 0) ndo_s = nndbuf[(size_t)bh * NC + c];
  }
  __syncthreads();
  size_t m0 = (size_t)b * S_ + (size_t)c * CH;
  int g  = t & 7;
  int l0 = t >> 3;
  float ndo = ndo_s;
  for (int li = l0; li < 64; li += 32) {
    size_t a = (m0 + li) * DM + h * DN + g * 8;
    u16x8 v = *reinterpret_cast<u16x8*>(&ybuf[a]);
    float sd = sdo[li];
    float rec = 1.f / (nrm[li] + ndo * sd);
    u16x8 o;
#pragma unroll
    for (int jj = 0; jj < 8; ++jj) {
      float yd = bf2f(v[jj]);
      o[jj] = f2bf((yd + sto[g * 8 + jj] * sd) * rec);
    }
    *reinterpret_cast<u16x8*>(&ybuf[a]) = o;
  }
}

// ===================== launch =====================
extern "C" void kernel_launch(void* const* d_in, const int* in_sizes, int n_in,
                              void* d_out, int out_size, void* d_ws, size_t ws_size,
                              hipStream_t stream) {
  const float* x          = (const float*)d_in[0];
  const float* in_proj_w  = (const float*)d_in[1];
  const float* conv_w     = (const float*)d_in[2];
  const float* conv_b     = (const float*)d_in[3];
  const float* w_base     = (const float*)d_in[4];
  const float* out_proj_w = (const float*)d_in[5];
  float* out = (float*)d_out;
  char* ws = (char*)d_ws;

  // workspace layout (~146 MB)
  u16*   wbf_in  = (u16*)  (ws + 0);
  u16*   wbf_out = (u16*)  (ws + 2097152);
  float* wbufT   = (float*)(ws + 4194304);
  float* Acum    = (float*)(ws + 6291456);
  float* acbuf   = (float*)(ws + 8388608);
  float* normd   = (float*)(ws + 8421376);
  float* states  = (float*)(ws + 10518528);
  float* ndbuf   = (float*)(ws + 12615680);
  float* nstates = (float*)(ws + 12648448);
  float* nndbuf  = (float*)(ws + 14745600);
  u16*   xbf     = (u16*)  (ws + 14778368);   // [M][1024] bf16 of x; reused as ybuf
  u16*   xibf    = (u16*)  (ws + 81887232);   // [M][1024] bf16 xi (in_proj out)
  u16*   ybuf    = xbf;

  wgemm<<<512, 256, 0, stream>>>(x, in_proj_w, wbufT, xbf);
  cvt32to16<<<512, 256, 0, stream>>>(in_proj_w, wbf_in);
  cvt32to16<<<512, 256, 0, stream>>>(out_proj_w, wbf_out);
  bgemm<1><<<2048, 256, 0, stream>>>(xbf, wbf_in, (void*)xibf, DM);
  chunk_kernel<<<8192, 256, 0, stream>>>(xibf, conv_w, conv_b, wbufT, w_base,
                                         ybuf, Acum, acbuf, normd, states, ndbuf);
  interchunk_kernel<<<128, 256, 0, stream>>>(acbuf, states, ndbuf, nstates, nndbuf);
  final_kernel<<<8192, 256, 0, stream>>>(Acum, normd, nstates, nndbuf, ybuf);
  bgemm<0><<<2048, 256, 0, stream>>>(ybuf, wbf_out, (void*)out, DM);
}